// Round 8
// baseline (282.701 us; speedup 1.0000x reference)
//
#include <hip/hip_runtime.h>

typedef unsigned short u16;
typedef short v8s __attribute__((ext_vector_type(8)));   // 8 bf16 in 4 VGPRs
typedef float f4 __attribute__((ext_vector_type(4)));

#define NROWS 262144
#define UNITS 8
#define TSTRIDE 2048
// 16384 tiles of 16 rows; unit = (tile, path); 32768 units.
// ROUND-8: one wave = one path, 8 units. 4096 waves -> 1024 blocks of 4 waves
// -> 4 blocks/CU (LDS 34.8 KB) = 16 waves/CU: 2x round-7 concurrency with
// clean contiguous DMA reads (the untested cell: r0 had concurrency+dirty
// access, r6/r7 clean access+low concurrency; all pinned at 2.5 TB/s).
// w = blockIdx*4+wave: path = w&1, t0 = w>>1; waves 2k,2k+1 share tile t0
// (2nd DMA of same lines hits L2 -> no extra HBM fetch, proven r6->r7).

__device__ __forceinline__ u16 f2bf(float f) {
  union { float f; unsigned int i; } x; x.f = f;
  unsigned int r = x.i + 0x7fffu + ((x.i >> 16) & 1u);   // round-nearest-even
  return (u16)(r >> 16);
}

typedef const __attribute__((address_space(1))) float* gp1;
typedef __attribute__((address_space(3))) float* lp3;
// DMA 64 lanes x 16B -> LDS[base + lane*16]; global addr per-lane.
__device__ __forceinline__ void g2l16(const float* g, float* l) {
  __builtin_amdgcn_global_load_lds((gp1)g, (lp3)l, 16, 0, 0);
}

#define FENCE_LGKM0() asm volatile("s_waitcnt lgkmcnt(0)" ::: "memory")
#define FENCE_VM(n)   asm volatile("s_waitcnt vmcnt(" #n ")" ::: "memory")

// ---------------------------------------------------------------------------
// Kernel 1: fold M = Wo @ Wv (f32 math -> bf16), c = Wo @ bv + bo (f32),
// copy g/be (f32) into ws. grid 8 x 256 -> 2048 items = mat(2) x n(64) x kg(16)
// ---------------------------------------------------------------------------
__global__ void fuse_weights(const float* __restrict__ Wo1, const float* __restrict__ Wv2,
                             const float* __restrict__ bv2, const float* __restrict__ bo1,
                             const float* __restrict__ Wo2, const float* __restrict__ Wv1,
                             const float* __restrict__ bv1, const float* __restrict__ bo2,
                             const float* __restrict__ g1,  const float* __restrict__ be1,
                             const float* __restrict__ g2,  const float* __restrict__ be2,
                             u16* __restrict__ M1, u16* __restrict__ M2,
                             float* __restrict__ cgb) {
  int item = blockIdx.x * 256 + threadIdx.x;   // 0..2047
  int mat = item >> 10;                        // 0: path1, 1: path2
  int n   = (item >> 4) & 63;                  // output feature (row of M)
  int k0  = (item & 15) * 4;                   // 4 columns per thread
  const float* Wo = mat ? Wo2 : Wo1;
  const float* Wv = mat ? Wv1 : Wv2;
  float a0 = 0.f, a1 = 0.f, a2 = 0.f, a3 = 0.f;
  for (int j = 0; j < 64; ++j) {
    float w = Wo[n * 64 + j];
    f4 wv = *(const f4*)(Wv + j * 64 + k0);
    a0 += w * wv[0];
    a1 += w * wv[1];
    a2 += w * wv[2];
    a3 += w * wv[3];
  }
  u16* M = mat ? M2 : M1;
  M[n * 64 + k0 + 0] = f2bf(a0);
  M[n * 64 + k0 + 1] = f2bf(a1);
  M[n * 64 + k0 + 2] = f2bf(a2);
  M[n * 64 + k0 + 3] = f2bf(a3);
  if ((item & 15) == 0) {
    const float* bv = mat ? bv1 : bv2;
    const float* bo = mat ? bo2 : bo1;
    float s = bo[n];
    for (int j = 0; j < 64; ++j) s += Wo[n * 64 + j] * bv[j];
    cgb[mat * 64 + n] = s;                       // c1 @0, c2 @64
    const float* g  = mat ? g2 : g1;
    const float* be = mat ? be2 : be1;
    cgb[128 + mat * 128 + n] = g[n];             // g1 @128, g2 @256
    cgb[192 + mat * 128 + n] = be[n];            // be1 @192, be2 @320
  }
}

// ---------------------------------------------------------------------------
// Kernel 2 (ROUND-8): max-concurrency single-buffer DMA pipeline.
// Per unit (in-order vmcnt analysis):
//   FENCE_VM(4)   -- waits this unit's 8 DMAs (oldest); prev 4 stores ride
//   ds_reads      -- tile -> regs (x-frags + residual)
//   FENCE_LGKM0   -- reg data ready AND buffer free for overwrite
//   stage(next)   -- 8 DMAs issue (overlap = rest of this unit's compute)
//   sched_barrier -- pin DMA issue slot (compiler must not sink it)
//   compute+LN    -- MFMA etc.
//   4 stores      -- newest in queue; never inside any wait window
// Outstanding at next fence: [DMA(8) old, stores(4) new] -> VM(4) retires
// exactly the 8 DMAs. Stores never drained in-loop.
// LDS: sbuf[4 waves][2 tiles][1040] (1KB DMA block + 16B skew per 4 rows)
// = 33.3 KB + scgb 1.5 KB -> 4 blocks/CU.
// ---------------------------------------------------------------------------
__global__ __launch_bounds__(256, 4) void xattn(
    const float* __restrict__ v1, const float* __restrict__ v2,
    const u16* __restrict__ M1, const u16* __restrict__ M2,
    const float* __restrict__ cgb,
    float* __restrict__ out1, float* __restrict__ out2) {
  const int lane = threadIdx.x & 63;
  const int wave = threadIdx.x >> 6;
  const int quad = lane >> 4;
  const int l15  = lane & 15;

  const int w    = blockIdx.x * 4 + wave;   // 0..4095
  const int path = w & 1;
  const int t0   = w >> 1;                  // 0..2047

  // [wave][v1=0/v2=1][4 blocks x 260 dwords]; block = 4 rows x 64 f32 + 16B skew
  __shared__ float sbuf[4][2][1040];
  __shared__ float scgb[384];
  if (threadIdx.x < 96)
    ((f4*)scgb)[threadIdx.x] = ((const f4*)cgb)[threadIdx.x];
  __syncthreads();   // scgb visible

  const u16* M  = path ? M2 : M1;
  float*   outp = path ? out2 : out1;
  const int xi  = path ^ 1;   // x tile: path0 -> v2(idx1), path1 -> v1(idx0)
  const int ri  = path;       // residual: path0 -> v1(idx0), path1 -> v2(idx1)
  const int coff = path * 64;
  const int goff = 128 + path * 128;
  const int boff = 192 + path * 128;

  // Weight A-fragments: A[m = mt*16+l15][k = ks*32+quad*8+j]
  v8s a[4][2];
#pragma unroll
  for (int mt = 0; mt < 4; ++mt)
#pragma unroll
    for (int ks = 0; ks < 2; ++ks)
      a[mt][ks] = *(const v8s*)(M + (mt * 16 + l15) * 64 + ks * 32 + quad * 8);

  // padded row offset inside a tile buffer (dwords)
  const int ro = (l15 >> 2) * 260 + (l15 & 3) * 64;

  auto stage = [&](int tile) {
    const float* g1v = v1 + (size_t)tile * 1024 + lane * 4;
    const float* g2v = v2 + (size_t)tile * 1024 + lane * 4;
    float* l1 = &sbuf[wave][0][0];
    float* l2 = &sbuf[wave][1][0];
#pragma unroll
    for (int j = 0; j < 4; ++j) {
      g2l16(g1v + j * 256, l1 + j * 260);   // 4 rows (1KB) per DMA, skewed
      g2l16(g2v + j * 256, l2 + j * 260);
    }
  };

  stage(t0);   // prologue: unit 0

#pragma unroll
  for (int it = 0; it < UNITS; ++it) {
    // wait for this unit's 8 DMAs (oldest); stores stay in flight
    if (it == 0) { FENCE_VM(0); }
    else         { FENCE_VM(4); }

    const float* xw = &sbuf[wave][xi][0];
    const float* rw = &sbuf[wave][ri][0];
    f4 x0 = *(const f4*)(xw + ro + quad * 8);
    f4 x1 = *(const f4*)(xw + ro + quad * 8 + 4);
    f4 x2 = *(const f4*)(xw + ro + quad * 8 + 32);
    f4 x3 = *(const f4*)(xw + ro + quad * 8 + 36);
    f4 rv[4];
#pragma unroll
    for (int mt = 0; mt < 4; ++mt)
      rv[mt] = *(const f4*)(rw + ro + mt * 16 + quad * 4);

    FENCE_LGKM0();                          // reg data ready; buffer free
    if (it + 1 < UNITS) stage(t0 + (it + 1) * TSTRIDE);
    __builtin_amdgcn_sched_barrier(0);      // pin DMA issue before compute

    // ---- convert B-fragment: B[k=quad*8+j][n=l15] = X[row l15][k] ----
    v8s b0, b1;
#pragma unroll
    for (int j = 0; j < 4; ++j) {
      b0[j]     = (short)f2bf(x0[j]);
      b0[j + 4] = (short)f2bf(x1[j]);
      b1[j]     = (short)f2bf(x2[j]);
      b1[j + 4] = (short)f2bf(x3[j]);
    }

    f4 acc[4];
#pragma unroll
    for (int mt = 0; mt < 4; ++mt) {
      f4 c = {0.f, 0.f, 0.f, 0.f};
      c = __builtin_amdgcn_mfma_f32_16x16x32_bf16(a[mt][0], b0, c, 0, 0, 0);
      c = __builtin_amdgcn_mfma_f32_16x16x32_bf16(a[mt][1], b1, c, 0, 0, 0);
      acc[mt] = c;
    }

    // ---- +bias +residual, LN stats ----
    float sum = 0.f, sq = 0.f;
#pragma unroll
    for (int mt = 0; mt < 4; ++mt) {
      const int fo = mt * 16 + quad * 4;
      f4 cf = *(const f4*)(scgb + coff + fo);
#pragma unroll
      for (int j = 0; j < 4; ++j) {
        float t = acc[mt][j] + cf[j] + rv[mt][j];
        acc[mt][j] = t;
        sum += t;
        sq  += t * t;
      }
    }
    // batch row split across lanes {l, l^16, l^32, l^48}: butterfly over quads
    sum += __shfl_xor(sum, 16, 64);
    sq  += __shfl_xor(sq,  16, 64);
    sum += __shfl_xor(sum, 32, 64);
    sq  += __shfl_xor(sq,  32, 64);
    float mean = sum * 0.015625f;
    float var  = sq * 0.015625f - mean * mean;
    float rstd = rsqrtf(var + 1e-5f);

    const size_t r0 = (size_t)(t0 + it * TSTRIDE) * 16;
    float* orow = outp + (r0 + l15) * 64 + quad * 4;
#pragma unroll
    for (int mt = 0; mt < 4; ++mt) {
      const int fo = mt * 16 + quad * 4;
      f4 g  = *(const f4*)(scgb + goff + fo);
      f4 be = *(const f4*)(scgb + boff + fo);
      f4 o;
#pragma unroll
      for (int j = 0; j < 4; ++j)
        o[j] = (acc[mt][j] - mean) * rstd * g[j] + be[j];
      *(f4*)(orow + mt * 16) = o;                      // plain store (L2 ack)
    }
  }
}

extern "C" void kernel_launch(void* const* d_in, const int* in_sizes, int n_in,
                              void* d_out, int out_size, void* d_ws, size_t ws_size,
                              hipStream_t stream) {
  const float* v1  = (const float*)d_in[0];
  const float* v2  = (const float*)d_in[1];
  const float* Wv2 = (const float*)d_in[6];
  const float* bv2 = (const float*)d_in[7];
  const float* Wo1 = (const float*)d_in[8];
  const float* bo1 = (const float*)d_in[9];
  const float* Wv1 = (const float*)d_in[14];
  const float* bv1 = (const float*)d_in[15];
  const float* Wo2 = (const float*)d_in[16];
  const float* bo2 = (const float*)d_in[17];
  const float* g1  = (const float*)d_in[18];
  const float* be1 = (const float*)d_in[19];
  const float* g2  = (const float*)d_in[20];
  const float* be2 = (const float*)d_in[21];

  u16* M1 = (u16*)d_ws;                         // 4096 bf16
  u16* M2 = M1 + 4096;                          // 4096 bf16
  float* cgb = (float*)((char*)d_ws + 16384);   // 384 f32: c1,c2,g1,be1,g2,be2

  float* out1 = (float*)d_out;
  float* out2 = out1 + (size_t)NROWS * 64;

  fuse_weights<<<8, 256, 0, stream>>>(Wo1, Wv2, bv2, bo1, Wo2, Wv1, bv1, bo2,
                                      g1, be1, g2, be2, M1, M2, cgb);
  xattn<<<1024, 256, 0, stream>>>(v1, v2, M1, M2, cgb, out1, out2);
}